// Round 7
// baseline (16924.072 us; speedup 1.0000x reference)
//
#include <hip/hip_runtime.h>
#include <cstdint>
#include <cstddef>

// ---------------- problem constants ----------------
#define SEQ    512
#define BATCH  128
#define EMB    512
#define HID    1024
#define KTOT   1536   // EMB + HID fused K
#define NOUT   8

// ---------------- decomposition ----------------
// 8 independent row-groups (16 batch rows each), 16 col-blocks of 256 gate-cols.
// Block = 1024 threads = 16 waves: wave (cg,kq) = 64 gate-cols x 384 fused-K.
// W lives entirely in registers (192 VGPR/lane). Cross-kq reduce via LDS.
#define RG     8
#define NBQ    16            // col-blocks per row-group
#define NBLK   (RG*NBQ)      // 128 blocks
#define ROWS   16            // batch rows per block
#define KQL    384           // fused K per wave
#define NCH    12            // 32-wide K chunks per wave
#define PSTR   65            // pacc row stride (f32 words, padded)

typedef unsigned short u16;
typedef unsigned int   u32;
typedef unsigned long long u64;
typedef __attribute__((ext_vector_type(8))) __bf16 bf16x8;
typedef __attribute__((ext_vector_type(4))) float  f32x4;
typedef __attribute__((ext_vector_type(4))) float  float4v;
typedef __attribute__((ext_vector_type(4))) u16    u16x4;

// ---------------- workspace layout ----------------
#define OFF_X    0ull
#define SZ_X     ((size_t)SEQ*BATCH*EMB*2)      // 64 MB  bf16 x [S][B][E]
#define OFF_W    (OFF_X + SZ_X)
#define SZ_W     ((size_t)4*HID*KTOT*2)         // 12 MB  bf16 packed weights [gc][k]
#define OFF_H0   (OFF_W + SZ_W)
#define SZ_H     ((size_t)BATCH*HID*2)          // 256 KB bf16 h buffer
#define OFF_H1   (OFF_H0 + SZ_H)
#define OFF_CNT  (OFF_H1 + SZ_H)
#define SZ_CNT   ((size_t)SEQ*RG*64)            // 256 KB arrive lines cnt[t][rg]
#define OFF_GO   (OFF_CNT + SZ_CNT)
#define SZ_GO    ((size_t)RG*64)                // go[rg] lines
#define WS_NEED  (OFF_GO + SZ_GO)

#define SMEM_BYTES ((size_t)16*ROWS*PSTR*4)     // 66560 B partial-acc buffer

// ---------------- helpers ----------------
__device__ inline u16 f2b(float f) {            // f32 -> bf16 RNE
  uint32_t u = __builtin_bit_cast(uint32_t, f);
  u = u + 0x7FFFu + ((u >> 16) & 1u);
  return (u16)(u >> 16);
}
__device__ inline float b2f(u16 u) {
  uint32_t v = ((uint32_t)u) << 16;
  return __builtin_bit_cast(float, v);
}
__device__ inline float sigm(float x) { return 1.0f / (1.0f + __expf(-x)); }
__device__ inline float tanh_(float x) {
  x = fminf(fmaxf(x, -15.f), 15.f);
  float e = __expf(2.f * x);
  return (e - 1.f) / (e + 1.f);
}
__device__ inline f32x4 mfma16(bf16x8 a, bf16x8 b, f32x4 c) {
  return __builtin_amdgcn_mfma_f32_16x16x32_bf16(a, b, c, 0, 0, 0);
}
struct QQ { u64 x, y; };
__device__ inline bf16x8 qq2v(u64 lo, u64 hi) {
  QQ q; q.x = lo; q.y = hi;
  return __builtin_bit_cast(bf16x8, q);
}

// ---------------- prep: embedding gather -> bf16 x[t][b][e] ----------------
__global__ void embed_kernel(const int* __restrict__ ids,
                             const float* __restrict__ emb,
                             u16* __restrict__ x) {
  int bid = blockIdx.x;            // t*128 + b
  int t = bid >> 7, b = bid & 127;
  int idx = ids[b * SEQ + t];
  const float4v* src = (const float4v*)(emb + (size_t)idx * EMB);
  float4v v = src[threadIdx.x];    // 128 threads x float4 = 512 floats
  u16x4 o;
  o.x = f2b(v.x); o.y = f2b(v.y); o.z = f2b(v.z); o.w = f2b(v.w);
  *(u16x4*)(x + (size_t)bid * EMB + threadIdx.x * 4) = o;
}

// ---------------- prep: pack fused weights, unit-major gate order -----------
// gc = unit*4 + q  (q: 0=i,1=f,2=g,3=o)  ->  original row = q*HID + unit
// Wp[gc][k], k fused [E | H]
__global__ void wpack_kernel(const float* __restrict__ Wih,
                             const float* __restrict__ Whh,
                             u16* __restrict__ Wp) {
  int gc = blockIdx.x;             // 0..4095
  int unit = gc >> 2, q = gc & 3;
  int row = q * HID + unit;
  u16* dst = Wp + (size_t)gc * KTOT;
  for (int k = threadIdx.x; k < KTOT; k += 256) {
    float v = (k < EMB) ? Wih[(size_t)row * EMB + k]
                        : Whh[(size_t)row * HID + (k - EMB)];
    dst[k] = f2b(v);
  }
}

// ---------------- persistent LSTM recurrence ----------------
__global__ __launch_bounds__(1024, 1) void lstm_kernel(
    const u16* __restrict__ x,     // [SEQ][BATCH][EMB] bf16
    const u16* __restrict__ Wp,    // [4096][KTOT] bf16 packed
    const float* __restrict__ bias,// [4*HID] f32 (original gate-major layout)
    u16* __restrict__ h0,          // [BATCH][HID] bf16 (holds h_last at end)
    u16* __restrict__ h1,          // double buffer B
    u32* __restrict__ cnt,         // [SEQ][RG] arrive lines (zeroed)
    u32* __restrict__ go)          // [RG] go lines (zeroed)
{
  extern __shared__ float pacc[];  // [16 waves][16 rows][PSTR]

  const int tid  = threadIdx.x;
  const int bid  = blockIdx.x;
  const int rg   = bid >> 4;       // row-group 0..7 (16 batch rows)
  const int nb   = bid & 15;       // col-block 0..15 (256 gate-cols)
  const int lane = tid & 63;
  const int wid  = tid >> 6;       // 16 waves
  const int kq   = wid & 3;        // K-quarter
  const int cg   = wid >> 2;       // 64-col group
  const int l15  = lane & 15;
  const int lhi  = lane >> 4;

  // #x-chunks in this wave's fused-K slice (chunks never straddle the E|H seam)
  const int nxc  = (kq == 0) ? 12 : (kq == 1 ? 4 : 0);
  const int xrow = rg * ROWS + l15;          // batch row for A-fragments

  // ---- W into registers: 48 x bf16x8 = 192 VGPR ----
  bf16x8 wreg[NCH][4];
  {
    const int colbase = nb * 256 + cg * 64;
    #pragma unroll
    for (int c = 0; c < NCH; ++c)
      #pragma unroll
      for (int ct = 0; ct < 4; ++ct)
        wreg[c][ct] = *(const bf16x8*)(Wp
            + (size_t)(colbase + ct * 16 + l15) * KTOT
            + kq * KQL + c * 32 + lhi * 8);
  }

  // ---- cell-update mapping: this lane owns cell (row r_, unit u_) ----
  const int u_   = l15;
  const int r_   = kq * 4 + lhi;             // 0..15
  const int unit = nb * 64 + cg * 16 + u_;
  const float bi_ = bias[unit];
  const float bf_ = bias[HID + unit];
  const float bg_ = bias[2 * HID + unit];
  const float bo_ = bias[3 * HID + unit];
  float cst = 0.f;

  u32* gol = &go[rg * 16];

  // ---- prologue: x fragments for t=0 ----
  bf16x8 afx[NCH];
  #pragma unroll
  for (int c = 0; c < NCH; ++c)
    if (c < nxc)
      afx[c] = *(const bf16x8*)(x + (size_t)xrow * EMB + kq * KQL + c * 32 + lhi * 8);

  #pragma unroll 1
  for (int t = 0; t < SEQ; ++t) {
    // ---- A: x-part MFMAs (pre-barrier; absorbs skew) + prefetch x(t+1) ----
    f32x4 acc[4];
    #pragma unroll
    for (int ct = 0; ct < 4; ++ct) acc[ct] = (f32x4){0.f, 0.f, 0.f, 0.f};
    #pragma unroll
    for (int c = 0; c < NCH; ++c)
      if (c < nxc) {
        #pragma unroll
        for (int ct = 0; ct < 4; ++ct)
          acc[ct] = mfma16(afx[c], wreg[c][ct], acc[ct]);
      }
    if (t < SEQ - 1) {
      #pragma unroll
      for (int c = 0; c < NCH; ++c)
        if (c < nxc)
          afx[c] = *(const bf16x8*)(x + ((size_t)(t + 1) * BATCH + xrow) * EMB
                                    + kq * KQL + c * 32 + lhi * 8);
    }

    // ---- B: wait for h(t) (published as go >= t at end of step t-1) ----
    if (t > 0) {
      if (tid == 0) {
        while (__hip_atomic_load(gol, __ATOMIC_RELAXED,
                                 __HIP_MEMORY_SCOPE_AGENT) < (u32)t)
          __builtin_amdgcn_s_sleep(1);
        __asm__ __volatile__("" ::: "memory");
      }
      __syncthreads();
    }

    // ---- C: h loads (sc1, bypass stale L2) + h-part MFMAs ----
    if (t > 0 && nxc < NCH) {
      const u16* hb = (t & 1) ? h1 : h0;
      bf16x8 afh[NCH];
      #pragma unroll
      for (int c = 0; c < NCH; ++c)
        if (c >= nxc) {
          const u64* p = (const u64*)(hb + (size_t)xrow * HID
                                      + (kq * KQL + c * 32 - EMB) + lhi * 8);
          u64 lo = __hip_atomic_load(p,     __ATOMIC_RELAXED, __HIP_MEMORY_SCOPE_AGENT);
          u64 hi = __hip_atomic_load(p + 1, __ATOMIC_RELAXED, __HIP_MEMORY_SCOPE_AGENT);
          afh[c] = qq2v(lo, hi);
        }
      #pragma unroll
      for (int c = 0; c < NCH; ++c)
        if (c >= nxc) {
          #pragma unroll
          for (int ct = 0; ct < 4; ++ct)
            acc[ct] = mfma16(afh[c], wreg[c][ct], acc[ct]);
        }
    }

    // ---- D: partial gate sums -> LDS ----
    {
      float* pw = &pacc[(size_t)((cg * 4 + kq) * ROWS + lhi * 4) * PSTR + l15];
      #pragma unroll
      for (int ct = 0; ct < 4; ++ct)
        #pragma unroll
        for (int rr = 0; rr < 4; ++rr)
          pw[rr * PSTR + ct * 16] = acc[ct][rr];
    }
    __syncthreads();

    // ---- E: reduce over kq, cell update, h store (1 cell per lane) ----
    {
      float s0 = 0.f, s1 = 0.f, s2 = 0.f, s3 = 0.f;
      #pragma unroll
      for (int k2 = 0; k2 < 4; ++k2) {
        const float* pr = &pacc[(size_t)((cg * 4 + k2) * ROWS + r_) * PSTR + u_ * 4];
        s0 += pr[0]; s1 += pr[1]; s2 += pr[2]; s3 += pr[3];
      }
      float iv = s0 + bi_, fv = s1 + bf_, gv = s2 + bg_, ov = s3 + bo_;
      float cn = sigm(fv) * cst + sigm(iv) * tanh_(gv);
      cst = cn;
      float hv = sigm(ov) * tanh_(cn);
      float other = __shfl_xor(hv, 1);        // unit partner u^1 (same row)
      if ((u_ & 1) == 0) {
        u16* hw = (t & 1) ? h0 : h1;
        u32 val = (u32)f2b(hv) | ((u32)f2b(other) << 16);
        u32* dst = (u32*)&hw[(size_t)(rg * ROWS + r_) * HID + unit];
        __hip_atomic_store(dst, val, __ATOMIC_RELAXED, __HIP_MEMORY_SCOPE_AGENT);
      }
    }

    // ---- F: drain stores, arrive (RMW-only line); last arriver posts go ----
    __syncthreads();   // per-wave vmcnt(0): h stores acked at coherence point
    if (t < SEQ - 1 && tid == 0) {
      u32* cl = &cnt[((size_t)t * RG + rg) * 16];
      u32 old = __hip_atomic_fetch_add(cl, 1u, __ATOMIC_RELAXED,
                                       __HIP_MEMORY_SCOPE_AGENT);
      if (old == (u32)(NBQ - 1))
        __hip_atomic_store(gol, (u32)(t + 1), __ATOMIC_RELAXED,
                           __HIP_MEMORY_SCOPE_AGENT);
    }
  }
}

// ---------------- classifier head: out = h_last @ W_out^T + b_out ----------
__global__ void head_kernel(const u16* __restrict__ h,
                            const float* __restrict__ Wout,
                            const float* __restrict__ bout,
                            float* __restrict__ out) {
  int b = blockIdx.x, l = threadIdx.x;
  const u64* hq = (const u64*)(h + (size_t)b * HID) + l * 4;
  u64 q[4];
  #pragma unroll
  for (int i = 0; i < 4; ++i)
    q[i] = __hip_atomic_load((const u64*)(hq + i),
                             __ATOMIC_RELAXED, __HIP_MEMORY_SCOPE_AGENT);
  float hv[16];
  #pragma unroll
  for (int i = 0; i < 4; ++i)
    #pragma unroll
    for (int j = 0; j < 4; ++j)
      hv[i * 4 + j] = b2f((u16)(q[i] >> (j * 16)));

  int k0 = l * 16;
  float p[NOUT];
  #pragma unroll
  for (int o = 0; o < NOUT; ++o) {
    p[o] = 0.f;
    #pragma unroll
    for (int j = 0; j < 16; ++j)
      p[o] += hv[j] * Wout[(size_t)o * HID + k0 + j];
  }
  #pragma unroll
  for (int o = 0; o < NOUT; ++o) {
    float v = p[o];
    #pragma unroll
    for (int off = 32; off > 0; off >>= 1) v += __shfl_down(v, off);
    if (l == 0) out[b * NOUT + o] = v + bout[o];
  }
}

// sentinel if workspace too small (distinguishable absmax ~1e9)
__global__ void sentinel_kernel(float* out, int n) {
  int i = blockIdx.x * 256 + threadIdx.x;
  if (i < n) out[i] = 1e9f;
}

extern "C" void kernel_launch(void* const* d_in, const int* in_sizes, int n_in,
                              void* d_out, int out_size, void* d_ws, size_t ws_size,
                              hipStream_t stream) {
  const int*   ids  = (const int*)d_in[0];
  const float* emb  = (const float*)d_in[1];
  const float* Wih  = (const float*)d_in[2];
  const float* Whh  = (const float*)d_in[3];
  const float* bias = (const float*)d_in[4];
  const float* Wout = (const float*)d_in[5];
  const float* bout = (const float*)d_in[6];
  float* out = (float*)d_out;

  if (ws_size < WS_NEED) {
    sentinel_kernel<<<(out_size + 255) / 256, 256, 0, stream>>>(out, out_size);
    return;
  }

  char* ws = (char*)d_ws;
  u16* x   = (u16*)(ws + OFF_X);
  u16* Wp  = (u16*)(ws + OFF_W);
  u16* h0  = (u16*)(ws + OFF_H0);
  u16* h1  = (u16*)(ws + OFF_H1);
  u32* cnt = (u32*)(ws + OFF_CNT);
  u32* go  = (u32*)(ws + OFF_GO);

  hipMemsetAsync(cnt, 0, SZ_CNT + SZ_GO, stream);  // barrier state (every call!)

  embed_kernel<<<SEQ * BATCH, 128, 0, stream>>>(ids, emb, x);
  wpack_kernel<<<4 * HID, 256, 0, stream>>>(Wih, Whh, Wp);

  hipFuncSetAttribute((const void*)lstm_kernel,
                      hipFuncAttributeMaxDynamicSharedMemorySize,
                      (int)SMEM_BYTES);
  lstm_kernel<<<NBLK, 1024, SMEM_BYTES, stream>>>(x, Wp, bias, h0, h1, cnt, go);

  // last write at t=511 (odd) -> h0
  head_kernel<<<BATCH, 64, 0, stream>>>(h0, Wout, bout, out);
}

// Round 8
// 4517.617 us; speedup vs baseline: 3.7462x; 3.7462x over previous
//
#include <hip/hip_runtime.h>
#include <cstdint>
#include <cstddef>

// ---------------- problem constants ----------------
#define SEQ    512
#define BATCH  128
#define EMB    512
#define HID    1024
#define KTOT   1536   // EMB + HID fused K
#define NOUT   8

// ---------------- decomposition ----------------
#define GN     128    // column-tile blocks over hidden units
#define UPB    8      // hidden units per block  (HID/GN)
#define NCOL   32     // gate columns per block  (4*UPB)
#define NBLK   256    // GN * GM, GM=2 batch halves
#define HBLK   128    // blocks per independent batch-half barrier
#define WPAD   1544   // padded K stride (elements) for LDS W

typedef unsigned short u16;
typedef unsigned int   u32;
typedef unsigned long long u64;
typedef __attribute__((ext_vector_type(8))) __bf16 bf16x8;
typedef __attribute__((ext_vector_type(4))) float  f32x4;
typedef __attribute__((ext_vector_type(4))) float  float4v;
typedef __attribute__((ext_vector_type(4))) u16    u16x4;

// ---------------- workspace layouts ----------------
#define OFF_X     0ull
#define SZ_X      ((size_t)SEQ*BATCH*EMB*2)      // 64 MB  bf16 x [S][B][E]
#define OFF_W     (OFF_X + SZ_X)
#define SZ_W      ((size_t)GN*NCOL*KTOT*2)       // 12 MB  bf16 packed weights
#define SZ_H      ((size_t)BATCH*HID*2)          // 256 KB one h buffer
#define SZ_CNT    ((size_t)SEQ*32*4)             // 64 KB  arrive lines
#define SZ_GO     (256ull)
// fallback (R6 double-buffer) layout
#define OFF_H0    (OFF_W + SZ_W)
#define OFF_H1    (OFF_H0 + SZ_H)
#define OFF_CNTD  (OFF_H1 + SZ_H)
#define OFF_GOD   (OFF_CNTD + SZ_CNT)
#define WS_DB     (OFF_GOD + SZ_GO)
// ring layout (h ring of SEQ+1 buffers -> never-stale L2-cacheable reads)
#define OFF_RING  (OFF_W + SZ_W)
#define SZ_RING   ((size_t)(SEQ+1)*BATCH*HID*2)  // ~134 MB
#define OFF_CNTR  (OFF_RING + SZ_RING)
#define OFF_GOR   (OFF_CNTR + SZ_CNT)
#define WS_RING   (OFF_GOR + SZ_GO)

#define SMEM_BYTES ((size_t)NCOL*WPAD*2 + 128)

// ---------------- helpers ----------------
__device__ inline u16 f2b(float f) {            // f32 -> bf16 RNE
  uint32_t u = __builtin_bit_cast(uint32_t, f);
  u = u + 0x7FFFu + ((u >> 16) & 1u);
  return (u16)(u >> 16);
}
__device__ inline float b2f(u16 u) {
  uint32_t v = ((uint32_t)u) << 16;
  return __builtin_bit_cast(float, v);
}
__device__ inline float sigm(float x) { return 1.0f / (1.0f + __expf(-x)); }
__device__ inline float tanh_(float x) {
  x = fminf(fmaxf(x, -15.f), 15.f);
  float e = __expf(2.f * x);
  return (e - 1.f) / (e + 1.f);
}
__device__ inline f32x4 mfma16(bf16x8 a, bf16x8 b, f32x4 c) {
  return __builtin_amdgcn_mfma_f32_16x16x32_bf16(a, b, c, 0, 0, 0);
}
struct QQ { u64 x, y; };
__device__ inline bf16x8 qq2v(u64 lo, u64 hi) {
  QQ q; q.x = lo; q.y = hi;
  return __builtin_bit_cast(bf16x8, q);
}

// ---------------- prep: embedding gather -> bf16 x[t][b][e] ----------------
__global__ void embed_kernel(const int* __restrict__ ids,
                             const float* __restrict__ emb,
                             u16* __restrict__ x) {
  int bid = blockIdx.x;            // t*128 + b
  int t = bid >> 7, b = bid & 127;
  int idx = ids[b * SEQ + t];
  const float4v* src = (const float4v*)(emb + (size_t)idx * EMB);
  float4v v = src[threadIdx.x];    // 128 threads x float4 = 512 floats
  u16x4 o;
  o.x = f2b(v.x); o.y = f2b(v.y); o.z = f2b(v.z); o.w = f2b(v.w);
  *(u16x4*)(x + (size_t)bid * EMB + threadIdx.x * 4) = o;
}

// ---------------- prep: pack [W_ih | W_hh] rows, gate-reordered, bf16 --------
__global__ void wpack_kernel(const float* __restrict__ Wih,
                             const float* __restrict__ Whh,
                             u16* __restrict__ Wr) {
  int bid = blockIdx.x;            // n*32 + c
  int c = bid & 31, n = bid >> 5;
  int q = c >> 3, u = c & 7;
  int row = q * HID + n * UPB + u;
  u16* dst = Wr + (size_t)bid * KTOT;
  for (int k = threadIdx.x; k < KTOT; k += 256) {
    float v = (k < EMB) ? Wih[(size_t)row * EMB + k]
                        : Whh[(size_t)row * HID + (k - EMB)];
    dst[k] = f2b(v);
  }
}

// =====================================================================
//  RING variant: h ring[SEQ+1]; plain cached reads, nt write-through
// =====================================================================
__global__ __launch_bounds__(256, 1) void lstm_ring_kernel(
    const u16* __restrict__ x,
    const u16* __restrict__ Wr,
    const float* __restrict__ bias,
    u16* __restrict__ ring,        // [SEQ+1][BATCH][HID] bf16; ring[0]=0
    u32* __restrict__ cnt,         // [SEQ][2] arrive lines (zeroed)
    u32* __restrict__ go)          // [2] go lines (zeroed)
{
  extern __shared__ char smem[];
  u16* Wl = (u16*)smem;

  const int tid  = threadIdx.x;
  const int bid  = blockIdx.x;
  const int n    = bid & (GN - 1);
  const int mh   = bid >> 7;
  const int lane = tid & 63;
  const int wid  = tid >> 6;

  const u16* wsrc = Wr + (size_t)n * NCOL * KTOT;
  for (int e = tid * 8; e < NCOL * KTOT; e += 256 * 8) {
    int c = e / KTOT;
    int k = e - c * KTOT;
    *(bf16x8*)&Wl[c * WPAD + k] = *(const bf16x8*)&wsrc[e];
  }
  __syncthreads();

  const int arow = lane & 15;
  const int kl   = (lane >> 4) * 8;
  const int bg   = mh * 64 + wid * 16 + arow;
  const int dcol = lane & 15;
  const int drow = (lane >> 4) * 4;

  const int  u    = lane & 7;
  const bool lolane = (lane & 8) == 0;
  const int  colu = n * UPB + u;

  const float bi_ = bias[colu];
  const float bf_ = bias[HID + colu];
  const float bg_ = bias[2 * HID + colu];
  const float bo_ = bias[3 * HID + colu];

  const u16* w0p = &Wl[(dcol) * WPAD + kl];
  const u16* w1p = &Wl[(16 + dcol) * WPAD + kl];

  float cst[4] = {0.f, 0.f, 0.f, 0.f};
  u32* gol = &go[mh * 16];

  bf16x8 xfrag[16];
  {
    const u16* xr = x + ((size_t)bg) * EMB + kl;
    #pragma unroll
    for (int kc = 0; kc < 16; ++kc) xfrag[kc] = *(const bf16x8*)(xr + kc * 32);
  }

  #pragma unroll 1
  for (int t = 0; t < SEQ; ++t) {
    // h(t) = ring[t] : PLAIN cached loads (first touch of these addresses
    // on this XCD happens strictly after all writes drained -> never stale)
    const u16* hr = ring + (size_t)t * BATCH * HID + (size_t)bg * HID + kl;

    bf16x8 hfrag[32];
    if (t > 0) {
      #pragma unroll
      for (int kc = 0; kc < 32; ++kc) hfrag[kc] = *(const bf16x8*)(hr + kc * 32);
    }

    f32x4 acc[2][2];
    #pragma unroll
    for (int i = 0; i < 2; ++i)
      #pragma unroll
      for (int j = 0; j < 2; ++j) acc[i][j] = (f32x4){0.f, 0.f, 0.f, 0.f};

    #pragma unroll
    for (int kc = 0; kc < 16; ++kc) {
      bf16x8 w0 = *(const bf16x8*)(w0p + kc * 32);
      bf16x8 w1 = *(const bf16x8*)(w1p + kc * 32);
      acc[kc & 1][0] = mfma16(xfrag[kc], w0, acc[kc & 1][0]);
      acc[kc & 1][1] = mfma16(xfrag[kc], w1, acc[kc & 1][1]);
    }

    if (t < SEQ - 1) {
      const u16* xr = x + ((size_t)(t + 1) * BATCH + bg) * EMB + kl;
      #pragma unroll
      for (int kc = 0; kc < 16; ++kc) xfrag[kc] = *(const bf16x8*)(xr + kc * 32);
    }

    if (t > 0) {
      #pragma unroll
      for (int kc = 0; kc < 32; ++kc) {
        bf16x8 w0 = *(const bf16x8*)(w0p + EMB + kc * 32);
        bf16x8 w1 = *(const bf16x8*)(w1p + EMB + kc * 32);
        acc[kc & 1][0] = mfma16(hfrag[kc], w0, acc[kc & 1][0]);
        acc[kc & 1][1] = mfma16(hfrag[kc], w1, acc[kc & 1][1]);
      }
    }

    f32x4 g0, g1;
    #pragma unroll
    for (int r = 0; r < 4; ++r) {
      g0[r] = acc[0][0][r] + acc[1][0][r];
      g1[r] = acc[0][1][r] + acc[1][1][r];
    }
    f32x4 p0, p1;
    #pragma unroll
    for (int r = 0; r < 4; ++r) {
      p0[r] = __shfl_xor(g0[r], 8);
      p1[r] = __shfl_xor(g1[r], 8);
    }

    float hv4[4];
    #pragma unroll
    for (int r = 0; r < 4; ++r) {
      float iv = (lolane ? g0[r] : p0[r]) + bi_;
      float fv = (lolane ? p0[r] : g0[r]) + bf_;
      float gv = (lolane ? g1[r] : p1[r]) + bg_;
      float ov = (lolane ? p1[r] : g1[r]) + bo_;
      float cn = sigm(fv) * cst[r] + sigm(iv) * tanh_(gv);
      cst[r] = cn;
      hv4[r] = sigm(ov) * tanh_(cn);
    }

    // h(t+1) -> ring[t+1]: u32 write-through, agent scope, NO L2 allocation
    u16* hw = ring + (size_t)(t + 1) * BATCH * HID;
    #pragma unroll
    for (int r = 0; r < 4; ++r) {
      float other = __shfl_xor(hv4[r], 1);
      bool doStore = (lolane ? (r < 2) : (r >= 2)) && ((u & 1) == 0);
      if (doStore) {
        u32 val = (u32)f2b(hv4[r]) | ((u32)f2b(other) << 16);
        u32* dst = (u32*)&hw[(size_t)(mh * 64 + wid * 16 + drow + r) * HID + colu];
        asm volatile("global_store_dword %0, %1, off sc0 sc1 nt"
                     :: "v"(dst), "v"(val) : "memory");
      }
    }
    asm volatile("s_waitcnt vmcnt(0)" ::: "memory");   // stores acked at L3

    __syncthreads();
    if (t == SEQ - 1) break;
    if (tid == 0) {
      u32* cl = &cnt[((size_t)t * 2 + mh) * 16];
      u32 old = __hip_atomic_fetch_add(cl, 1u, __ATOMIC_RELAXED,
                                       __HIP_MEMORY_SCOPE_AGENT);
      if (old == (u32)(HBLK - 1)) {
        __hip_atomic_store(gol, (u32)(t + 1), __ATOMIC_RELAXED,
                           __HIP_MEMORY_SCOPE_AGENT);
      } else {
        while (__hip_atomic_load(gol, __ATOMIC_RELAXED,
                                 __HIP_MEMORY_SCOPE_AGENT) < (u32)(t + 1)) {
          __builtin_amdgcn_s_sleep(2);
        }
      }
      __asm__ __volatile__("" ::: "memory");
    }
    __syncthreads();
  }
}

// =====================================================================
//  FALLBACK: exact R6 double-buffer kernel (sc1 bypass reads)
// =====================================================================
__global__ __launch_bounds__(256, 1) void lstm_db_kernel(
    const u16* __restrict__ x,
    const u16* __restrict__ Wr,
    const float* __restrict__ bias,
    u16* __restrict__ h0,
    u16* __restrict__ h1,
    u32* __restrict__ cnt,
    u32* __restrict__ go)
{
  extern __shared__ char smem[];
  u16* Wl = (u16*)smem;

  const int tid  = threadIdx.x;
  const int bid  = blockIdx.x;
  const int n    = bid & (GN - 1);
  const int mh   = bid >> 7;
  const int lane = tid & 63;
  const int wid  = tid >> 6;

  const u16* wsrc = Wr + (size_t)n * NCOL * KTOT;
  for (int e = tid * 8; e < NCOL * KTOT; e += 256 * 8) {
    int c = e / KTOT;
    int k = e - c * KTOT;
    *(bf16x8*)&Wl[c * WPAD + k] = *(const bf16x8*)&wsrc[e];
  }
  __syncthreads();

  const int arow = lane & 15;
  const int kl   = (lane >> 4) * 8;
  const int bg   = mh * 64 + wid * 16 + arow;
  const int dcol = lane & 15;
  const int drow = (lane >> 4) * 4;

  const int  u    = lane & 7;
  const bool lolane = (lane & 8) == 0;
  const int  colu = n * UPB + u;

  const float bi_ = bias[colu];
  const float bf_ = bias[HID + colu];
  const float bg_ = bias[2 * HID + colu];
  const float bo_ = bias[3 * HID + colu];

  const u16* w0p = &Wl[(dcol) * WPAD + kl];
  const u16* w1p = &Wl[(16 + dcol) * WPAD + kl];

  float cst[4] = {0.f, 0.f, 0.f, 0.f};
  u32* gol = &go[mh * 16];

  bf16x8 xfrag[16];
  {
    const u16* xr = x + ((size_t)bg) * EMB + kl;
    #pragma unroll
    for (int kc = 0; kc < 16; ++kc) xfrag[kc] = *(const bf16x8*)(xr + kc * 32);
  }

  #pragma unroll 1
  for (int t = 0; t < SEQ; ++t) {
    const u16* hr_buf = (t & 1) ? h1 : h0;
    u16*       hw_buf = (t & 1) ? h0 : h1;
    const u64* hq = (const u64*)(hr_buf + (size_t)bg * HID + kl);

    bf16x8 hfrag[32];
    if (t > 0) {
      #pragma unroll
      for (int kc = 0; kc < 32; ++kc) {
        u64 lo = __hip_atomic_load((const u64*)(hq + kc * 8),
                                   __ATOMIC_RELAXED, __HIP_MEMORY_SCOPE_AGENT);
        u64 hi = __hip_atomic_load((const u64*)(hq + kc * 8 + 1),
                                   __ATOMIC_RELAXED, __HIP_MEMORY_SCOPE_AGENT);
        hfrag[kc] = qq2v(lo, hi);
      }
    }

    f32x4 acc[2][2];
    #pragma unroll
    for (int i = 0; i < 2; ++i)
      #pragma unroll
      for (int j = 0; j < 2; ++j) acc[i][j] = (f32x4){0.f, 0.f, 0.f, 0.f};

    #pragma unroll
    for (int kc = 0; kc < 16; ++kc) {
      bf16x8 w0 = *(const bf16x8*)(w0p + kc * 32);
      bf16x8 w1 = *(const bf16x8*)(w1p + kc * 32);
      acc[kc & 1][0] = mfma16(xfrag[kc], w0, acc[kc & 1][0]);
      acc[kc & 1][1] = mfma16(xfrag[kc], w1, acc[kc & 1][1]);
    }

    if (t < SEQ - 1) {
      const u16* xr = x + ((size_t)(t + 1) * BATCH + bg) * EMB + kl;
      #pragma unroll
      for (int kc = 0; kc < 16; ++kc) xfrag[kc] = *(const bf16x8*)(xr + kc * 32);
    }

    if (t > 0) {
      #pragma unroll
      for (int kc = 0; kc < 32; ++kc) {
        bf16x8 w0 = *(const bf16x8*)(w0p + EMB + kc * 32);
        bf16x8 w1 = *(const bf16x8*)(w1p + EMB + kc * 32);
        acc[kc & 1][0] = mfma16(hfrag[kc], w0, acc[kc & 1][0]);
        acc[kc & 1][1] = mfma16(hfrag[kc], w1, acc[kc & 1][1]);
      }
    }

    f32x4 g0, g1;
    #pragma unroll
    for (int r = 0; r < 4; ++r) {
      g0[r] = acc[0][0][r] + acc[1][0][r];
      g1[r] = acc[0][1][r] + acc[1][1][r];
    }
    f32x4 p0, p1;
    #pragma unroll
    for (int r = 0; r < 4; ++r) {
      p0[r] = __shfl_xor(g0[r], 8);
      p1[r] = __shfl_xor(g1[r], 8);
    }

    float hv4[4];
    #pragma unroll
    for (int r = 0; r < 4; ++r) {
      float iv = (lolane ? g0[r] : p0[r]) + bi_;
      float fv = (lolane ? p0[r] : g0[r]) + bf_;
      float gv = (lolane ? g1[r] : p1[r]) + bg_;
      float ov = (lolane ? p1[r] : g1[r]) + bo_;
      float cn = sigm(fv) * cst[r] + sigm(iv) * tanh_(gv);
      cst[r] = cn;
      hv4[r] = sigm(ov) * tanh_(cn);
    }

    #pragma unroll
    for (int r = 0; r < 4; ++r) {
      float other = __shfl_xor(hv4[r], 1);
      bool doStore = (lolane ? (r < 2) : (r >= 2)) && ((u & 1) == 0);
      if (doStore) {
        u32 val = (u32)f2b(hv4[r]) | ((u32)f2b(other) << 16);
        u32* dst = (u32*)&hw_buf[(size_t)(mh * 64 + wid * 16 + drow + r) * HID + colu];
        __hip_atomic_store(dst, val, __ATOMIC_RELAXED, __HIP_MEMORY_SCOPE_AGENT);
      }
    }

    __syncthreads();
    if (t == SEQ - 1) break;
    if (tid == 0) {
      u32* cl = &cnt[((size_t)t * 2 + mh) * 16];
      u32 old = __hip_atomic_fetch_add(cl, 1u, __ATOMIC_RELAXED,
                                       __HIP_MEMORY_SCOPE_AGENT);
      if (old == (u32)(HBLK - 1)) {
        __hip_atomic_store(gol, (u32)(t + 1), __ATOMIC_RELAXED,
                           __HIP_MEMORY_SCOPE_AGENT);
      } else {
        while (__hip_atomic_load(gol, __ATOMIC_RELAXED,
                                 __HIP_MEMORY_SCOPE_AGENT) < (u32)(t + 1)) {
          __builtin_amdgcn_s_sleep(2);
        }
      }
      __asm__ __volatile__("" ::: "memory");
    }
    __syncthreads();
  }
}

// ---------------- classifier heads ----------------
__global__ void head_plain_kernel(const u16* __restrict__ h,
                                  const float* __restrict__ Wout,
                                  const float* __restrict__ bout,
                                  float* __restrict__ out) {
  int b = blockIdx.x, l = threadIdx.x;
  float p[NOUT];
  #pragma unroll
  for (int o = 0; o < NOUT; ++o) p[o] = 0.f;
  for (int k = l; k < HID; k += 64) {
    float hv = b2f(h[(size_t)b * HID + k]);
    #pragma unroll
    for (int o = 0; o < NOUT; ++o) p[o] += hv * Wout[(size_t)o * HID + k];
  }
  #pragma unroll
  for (int o = 0; o < NOUT; ++o) {
    float v = p[o];
    #pragma unroll
    for (int off = 32; off > 0; off >>= 1) v += __shfl_down(v, off);
    if (l == 0) out[b * NOUT + o] = v + bout[o];
  }
}

__global__ void head_sc1_kernel(const u16* __restrict__ h,
                                const float* __restrict__ Wout,
                                const float* __restrict__ bout,
                                float* __restrict__ out) {
  int b = blockIdx.x, l = threadIdx.x;
  const u64* hq = (const u64*)(h + (size_t)b * HID) + l * 4;
  u64 q[4];
  #pragma unroll
  for (int i = 0; i < 4; ++i)
    q[i] = __hip_atomic_load((const u64*)(hq + i),
                             __ATOMIC_RELAXED, __HIP_MEMORY_SCOPE_AGENT);
  float hv[16];
  #pragma unroll
  for (int i = 0; i < 4; ++i)
    #pragma unroll
    for (int j = 0; j < 4; ++j)
      hv[i * 4 + j] = b2f((u16)(q[i] >> (j * 16)));

  int k0 = l * 16;
  float p[NOUT];
  #pragma unroll
  for (int o = 0; o < NOUT; ++o) {
    p[o] = 0.f;
    #pragma unroll
    for (int j = 0; j < 16; ++j)
      p[o] += hv[j] * Wout[(size_t)o * HID + k0 + j];
  }
  #pragma unroll
  for (int o = 0; o < NOUT; ++o) {
    float v = p[o];
    #pragma unroll
    for (int off = 32; off > 0; off >>= 1) v += __shfl_down(v, off);
    if (l == 0) out[b * NOUT + o] = v + bout[o];
  }
}

// sentinel if workspace too small (distinguishable absmax ~1e9)
__global__ void sentinel_kernel(float* out, int n) {
  int i = blockIdx.x * 256 + threadIdx.x;
  if (i < n) out[i] = 1e9f;
}

extern "C" void kernel_launch(void* const* d_in, const int* in_sizes, int n_in,
                              void* d_out, int out_size, void* d_ws, size_t ws_size,
                              hipStream_t stream) {
  const int*   ids  = (const int*)d_in[0];
  const float* emb  = (const float*)d_in[1];
  const float* Wih  = (const float*)d_in[2];
  const float* Whh  = (const float*)d_in[3];
  const float* bias = (const float*)d_in[4];
  const float* Wout = (const float*)d_in[5];
  const float* bout = (const float*)d_in[6];
  float* out = (float*)d_out;

  char* ws = (char*)d_ws;
  u16* x  = (u16*)(ws + OFF_X);
  u16* Wr = (u16*)(ws + OFF_W);

  if (ws_size >= WS_RING) {
    // ------- ring path: L2-cacheable h reads -------
    u16* ring = (u16*)(ws + OFF_RING);
    u32* cnt  = (u32*)(ws + OFF_CNTR);
    u32* go   = (u32*)(ws + OFF_GOR);

    hipMemsetAsync(ring, 0, SZ_H, stream);            // ring[0] = h_0 = 0
    hipMemsetAsync(cnt, 0, SZ_CNT + SZ_GO, stream);   // barrier state

    embed_kernel<<<SEQ * BATCH, 128, 0, stream>>>(ids, emb, x);
    wpack_kernel<<<GN * NCOL, 256, 0, stream>>>(Wih, Whh, Wr);

    hipFuncSetAttribute((const void*)lstm_ring_kernel,
                        hipFuncAttributeMaxDynamicSharedMemorySize,
                        (int)SMEM_BYTES);
    lstm_ring_kernel<<<NBLK, 256, SMEM_BYTES, stream>>>(x, Wr, bias, ring, cnt, go);

    head_plain_kernel<<<BATCH, 64, 0, stream>>>(ring + (size_t)SEQ * BATCH * HID,
                                                Wout, bout, out);
  } else if (ws_size >= WS_DB) {
    // ------- fallback: exact R6 -------
    u16* h0  = (u16*)(ws + OFF_H0);
    u16* h1  = (u16*)(ws + OFF_H1);
    u32* cnt = (u32*)(ws + OFF_CNTD);
    u32* go  = (u32*)(ws + OFF_GOD);

    hipMemsetAsync(cnt, 0, SZ_CNT + SZ_GO, stream);

    embed_kernel<<<SEQ * BATCH, 128, 0, stream>>>(ids, emb, x);
    wpack_kernel<<<GN * NCOL, 256, 0, stream>>>(Wih, Whh, Wr);

    hipFuncSetAttribute((const void*)lstm_db_kernel,
                        hipFuncAttributeMaxDynamicSharedMemorySize,
                        (int)SMEM_BYTES);
    lstm_db_kernel<<<NBLK, 256, SMEM_BYTES, stream>>>(x, Wr, bias, h0, h1, cnt, go);

    head_sc1_kernel<<<BATCH, 64, 0, stream>>>(h0, Wout, bout, out);
  } else {
    sentinel_kernel<<<(out_size + 255) / 256, 256, 0, stream>>>(out, out_size);
  }
}

// Round 9
// 3123.594 us; speedup vs baseline: 5.4181x; 1.4463x over previous
//
#include <hip/hip_runtime.h>
#include <cstdint>
#include <cstddef>

// ---------------- problem constants ----------------
#define SEQ    512
#define BATCH  128
#define EMB    512
#define HID    1024
#define KTOT   1536   // EMB + HID fused K
#define NOUT   8

// ---------------- decomposition ----------------
// 4 row-groups (32 batch rows) x 64 col-blocks (64 gate-cols) = 256 blocks.
// Block = 256 thr = 4 waves = K-quarters (384 fused-K each).
// W entirely in VGPRs (192/lane). Cross-kq reduce via 34KB LDS (XOR-swizzled).
#define RG     4
#define NBQ    64            // col-blocks per row-group (sync domain size)
#define NBLK   (RG*NBQ)      // 256
#define ROWS   32            // batch rows per block

typedef unsigned short u16;
typedef unsigned int   u32;
typedef unsigned long long u64;
typedef __attribute__((ext_vector_type(8))) __bf16 bf16x8;
typedef __attribute__((ext_vector_type(4))) float  f32x4;
typedef __attribute__((ext_vector_type(4))) float  float4v;
typedef __attribute__((ext_vector_type(4))) u16    u16x4;

// ---------------- workspace layout ----------------
#define OFF_X    0ull
#define SZ_X     ((size_t)SEQ*BATCH*EMB*2)       // 64 MB  bf16 x [S][B][E]
#define OFF_W    (OFF_X + SZ_X)
#define SZ_W     ((size_t)4*HID*KTOT*2)          // 12 MB  bf16 Wp[gc][k], gc=unit*4+q
#define OFF_RING (OFF_W + SZ_W)
#define SZ_RING  ((size_t)(SEQ+1)*BATCH*HID*2)   // 134 MB h ring
#define OFF_CNT  (OFF_RING + SZ_RING)
#define SZ_CNT   ((size_t)16*RG*64)              // 4 KB arrive lines (recycled mod 16)
#define OFF_GO   (OFF_CNT + SZ_CNT)
#define SZ_GO    ((size_t)RG*64)
#define WS_NEED  (OFF_GO + SZ_GO)                // < R8's proven requirement

// ---------------- helpers ----------------
__device__ inline u16 f2b(float f) {            // f32 -> bf16 RNE
  uint32_t u = __builtin_bit_cast(uint32_t, f);
  u = u + 0x7FFFu + ((u >> 16) & 1u);
  return (u16)(u >> 16);
}
__device__ inline float b2f(u16 u) {
  uint32_t v = ((uint32_t)u) << 16;
  return __builtin_bit_cast(float, v);
}
__device__ inline float sigm(float x) { return 1.0f / (1.0f + __expf(-x)); }
__device__ inline float tanh_(float x) {
  x = fminf(fmaxf(x, -15.f), 15.f);
  float e = __expf(2.f * x);
  return (e - 1.f) / (e + 1.f);
}
__device__ inline f32x4 mfma16(bf16x8 a, bf16x8 b, f32x4 c) {
  return __builtin_amdgcn_mfma_f32_16x16x32_bf16(a, b, c, 0, 0, 0);
}

// ---------------- prep: embedding gather -> bf16 x[t][b][e] ----------------
__global__ void embed_kernel(const int* __restrict__ ids,
                             const float* __restrict__ emb,
                             u16* __restrict__ x) {
  int bid = blockIdx.x;            // t*128 + b
  int t = bid >> 7, b = bid & 127;
  int idx = ids[b * SEQ + t];
  const float4v* src = (const float4v*)(emb + (size_t)idx * EMB);
  float4v v = src[threadIdx.x];
  u16x4 o;
  o.x = f2b(v.x); o.y = f2b(v.y); o.z = f2b(v.z); o.w = f2b(v.w);
  *(u16x4*)(x + (size_t)bid * EMB + threadIdx.x * 4) = o;
}

// ---------------- prep: pack fused W, unit-major: gc=unit*4+q -----------
__global__ void wpack_kernel(const float* __restrict__ Wih,
                             const float* __restrict__ Whh,
                             u16* __restrict__ Wp) {
  int gc = blockIdx.x;             // 0..4095
  int unit = gc >> 2, q = gc & 3;
  int row = q * HID + unit;
  u16* dst = Wp + (size_t)gc * KTOT;
  for (int k = threadIdx.x; k < KTOT; k += 256) {
    float v = (k < EMB) ? Wih[(size_t)row * EMB + k]
                        : Whh[(size_t)row * HID + (k - EMB)];
    dst[k] = f2b(v);
  }
}

// ---------------- persistent LSTM recurrence (W in registers) --------------
__global__ __launch_bounds__(256, 1) void lstm_kernel(
    const u16* __restrict__ x,     // [SEQ][BATCH][EMB] bf16
    const u16* __restrict__ Wp,    // [4096][KTOT] bf16 packed
    const float* __restrict__ bias,// [4*HID] f32 gate-major
    u16* __restrict__ ring,        // [SEQ+1][BATCH][HID]; ring[0]=0
    u32* __restrict__ cnt,         // [16][RG] arrive lines (zeroed; recycled)
    u32* __restrict__ go)          // [RG] go lines (zeroed)
{
  __shared__ float pacc[4][ROWS][68];

  const int tid  = threadIdx.x;
  const int bid  = blockIdx.x;
  const int rg   = bid >> 6;       // row-group 0..3
  const int nb   = bid & 63;       // col-block 0..63
  const int lane = tid & 63;
  const int kq   = tid >> 6;       // wave = K-quarter
  const int l15  = lane & 15;
  const int lhi  = lane >> 4;

  // x-chunks within this wave's K-slice (fused k = kq*384 + c*32)
  const int nxc  = (kq == 0) ? 12 : (kq == 1 ? 4 : 0);
  const int arow = rg * ROWS + l15;          // A-fragment base batch row

  // ---- W into registers: 48 x bf16x8 = 192 VGPR ----
  bf16x8 wreg[12][4];
  {
    const int colbase = nb * 64;
    #pragma unroll
    for (int c = 0; c < 12; ++c)
      #pragma unroll
      for (int nt = 0; nt < 4; ++nt)
        wreg[c][nt] = *(const bf16x8*)(Wp
            + (size_t)(colbase + nt * 16 + l15) * KTOT
            + kq * 384 + c * 32 + lhi * 8);
  }

  // ---- cell-update mapping: thread -> (row urow, units 2up,2up+1) ----
  const int urow = tid >> 3;                 // 0..31
  const int up   = tid & 7;
  const int rowg = rg * ROWS + urow;
  float bs[2][4];
  #pragma unroll
  for (int k = 0; k < 2; ++k) {
    int ug = nb * 16 + 2 * up + k;
    #pragma unroll
    for (int q = 0; q < 4; ++q) bs[k][q] = bias[q * HID + ug];
  }
  float cst[2] = {0.f, 0.f};

  u32* gol = &go[rg * 16];

  // ---- prologue: x fragments for t=0 ----
  bf16x8 af[2][12];
  #pragma unroll
  for (int c = 0; c < 12; ++c)
    if (c < nxc) {
      #pragma unroll
      for (int mt = 0; mt < 2; ++mt)
        af[mt][c] = *(const bf16x8*)(x + (size_t)(arow + mt * 16) * EMB
                                     + kq * 384 + c * 32 + lhi * 8);
    }

  #pragma unroll 1
  for (int t = 0; t < SEQ; ++t) {
    // ---- A: pre-barrier x-part MFMAs (absorb skew; kq0/kq1 only) ----
    f32x4 acc[2][4];
    #pragma unroll
    for (int mt = 0; mt < 2; ++mt)
      #pragma unroll
      for (int nt = 0; nt < 4; ++nt) acc[mt][nt] = (f32x4){0.f, 0.f, 0.f, 0.f};
    #pragma unroll
    for (int c = 0; c < 12; ++c)
      if (c < nxc) {
        #pragma unroll
        for (int mt = 0; mt < 2; ++mt)
          #pragma unroll
          for (int nt = 0; nt < 4; ++nt)
            acc[mt][nt] = mfma16(af[mt][c], wreg[c][nt], acc[mt][nt]);
      }

    // ---- B: wait for h(t) ----
    if (t > 0) {
      if (tid == 0) {
        while (__hip_atomic_load(gol, __ATOMIC_RELAXED,
                                 __HIP_MEMORY_SCOPE_AGENT) < (u32)t)
          __builtin_amdgcn_s_sleep(1);
        __asm__ __volatile__("" ::: "memory");
      }
      __syncthreads();
    }

    // ---- C: h loads (plain cached; ring addr is never-stale) ----
    {
      const u16* hb = ring + (size_t)t * (BATCH * HID);
      #pragma unroll
      for (int c = 0; c < 12; ++c)
        if (c >= nxc) {
          #pragma unroll
          for (int mt = 0; mt < 2; ++mt)
            af[mt][c] = *(const bf16x8*)(hb + (size_t)(arow + mt * 16) * HID
                                         + (kq * 384 - 512 + c * 32) + lhi * 8);
        }
    }

    // ---- D: x prefetch t+1 (hides under h-MFMAs/epilogue) ----
    {
      int tn = (t + 1 < SEQ) ? (t + 1) : t;
      const u16* xb = x + (size_t)tn * (BATCH * EMB);
      #pragma unroll
      for (int c = 0; c < 12; ++c)
        if (c < nxc) {
          #pragma unroll
          for (int mt = 0; mt < 2; ++mt)
            af[mt][c] = *(const bf16x8*)(xb + (size_t)(arow + mt * 16) * EMB
                                         + kq * 384 + c * 32 + lhi * 8);
        }
    }

    // NOTE: for c<nxc, af was consumed in A before D overwrote it; for c>=nxc,
    // af holds h(t) fragments loaded in C. No slot is read before written.

    // ---- E: h-part MFMAs ----
    #pragma unroll
    for (int c = 0; c < 12; ++c)
      if (c >= nxc) {
        #pragma unroll
        for (int mt = 0; mt < 2; ++mt)
          #pragma unroll
          for (int nt = 0; nt < 4; ++nt)
            acc[mt][nt] = mfma16(af[mt][c], wreg[c][nt], acc[mt][nt]);
      }

    // ---- F: partials -> LDS (XOR col swizzle, conflict-free) ----
    #pragma unroll
    for (int mt = 0; mt < 2; ++mt)
      #pragma unroll
      for (int nt = 0; nt < 4; ++nt)
        #pragma unroll
        for (int rr = 0; rr < 4; ++rr) {
          int row = mt * 16 + lhi * 4 + rr;
          int c   = nt * 16 + l15;
          int pc  = (c & ~7) | ((c ^ row) & 7);
          pacc[kq][row][pc] = acc[mt][nt][rr];
        }
    __syncthreads();

    // ---- G: reduce over kq, cell update, packed nt store ----
    {
      float s[2][4];
      #pragma unroll
      for (int k = 0; k < 2; ++k)
        #pragma unroll
        for (int q = 0; q < 4; ++q) s[k][q] = bs[k][q];
      #pragma unroll
      for (int k2 = 0; k2 < 4; ++k2)
        #pragma unroll
        for (int cl = 0; cl < 8; ++cl) {
          int pc = 8 * up + ((cl ^ urow) & 7);
          s[cl >> 2][cl & 3] += pacc[k2][urow][pc];
        }
      float hv2[2];
      #pragma unroll
      for (int k = 0; k < 2; ++k) {
        float cn = sigm(s[k][1]) * cst[k] + sigm(s[k][0]) * tanh_(s[k][2]);
        cst[k] = cn;
        hv2[k] = sigm(s[k][3]) * tanh_(cn);
      }
      u32 val = (u32)f2b(hv2[0]) | ((u32)f2b(hv2[1]) << 16);
      u32* dst = (u32*)(ring + (size_t)(t + 1) * (BATCH * HID)
                        + (size_t)rowg * HID + nb * 16 + 2 * up);
      asm volatile("global_store_dword %0, %1, off sc0 sc1 nt"
                   :: "v"(dst), "v"(val) : "memory");
    }
    asm volatile("s_waitcnt vmcnt(0)" ::: "memory");   // stores acked at L3

    __syncthreads();
    if (t == SEQ - 1) break;
    if (tid == 0) {
      u32* cl_ = &cnt[((size_t)(t & 15) * RG + rg) * 16];
      u32 old = __hip_atomic_fetch_add(cl_, 1u, __ATOMIC_RELAXED,
                                       __HIP_MEMORY_SCOPE_AGENT);
      if (old == (u32)(NBQ - 1)) {
        __hip_atomic_store(cl_, 0u, __ATOMIC_RELAXED,
                           __HIP_MEMORY_SCOPE_AGENT);   // recycle for t+16
        __hip_atomic_store(gol, (u32)(t + 1), __ATOMIC_RELAXED,
                           __HIP_MEMORY_SCOPE_AGENT);   // publish
      }
    }
    // pollers wait at top of next iteration (after their x-MFMAs)
  }
}

// ---------------- classifier head: out = h_last @ W_out^T + b_out ----------
__global__ void head_kernel(const u16* __restrict__ h,
                            const float* __restrict__ Wout,
                            const float* __restrict__ bout,
                            float* __restrict__ out) {
  int b = blockIdx.x, l = threadIdx.x;
  float p[NOUT];
  #pragma unroll
  for (int o = 0; o < NOUT; ++o) p[o] = 0.f;
  for (int k = l; k < HID; k += 64) {
    float hv = b2f(h[(size_t)b * HID + k]);
    #pragma unroll
    for (int o = 0; o < NOUT; ++o) p[o] += hv * Wout[(size_t)o * HID + k];
  }
  #pragma unroll
  for (int o = 0; o < NOUT; ++o) {
    float v = p[o];
    #pragma unroll
    for (int off = 32; off > 0; off >>= 1) v += __shfl_down(v, off);
    if (l == 0) out[b * NOUT + o] = v + bout[o];
  }
}

// sentinel if workspace too small (distinguishable absmax ~1e9)
__global__ void sentinel_kernel(float* out, int n) {
  int i = blockIdx.x * 256 + threadIdx.x;
  if (i < n) out[i] = 1e9f;
}

extern "C" void kernel_launch(void* const* d_in, const int* in_sizes, int n_in,
                              void* d_out, int out_size, void* d_ws, size_t ws_size,
                              hipStream_t stream) {
  const int*   ids  = (const int*)d_in[0];
  const float* emb  = (const float*)d_in[1];
  const float* Wih  = (const float*)d_in[2];
  const float* Whh  = (const float*)d_in[3];
  const float* bias = (const float*)d_in[4];
  const float* Wout = (const float*)d_in[5];
  const float* bout = (const float*)d_in[6];
  float* out = (float*)d_out;

  if (ws_size < WS_NEED) {
    sentinel_kernel<<<(out_size + 255) / 256, 256, 0, stream>>>(out, out_size);
    return;
  }

  char* ws = (char*)d_ws;
  u16* x    = (u16*)(ws + OFF_X);
  u16* Wp   = (u16*)(ws + OFF_W);
  u16* ring = (u16*)(ws + OFF_RING);
  u32* cnt  = (u32*)(ws + OFF_CNT);
  u32* go   = (u32*)(ws + OFF_GO);

  hipMemsetAsync(ring, 0, (size_t)BATCH * HID * 2, stream);  // ring[0] = h_0 = 0
  hipMemsetAsync(cnt, 0, SZ_CNT + SZ_GO, stream);            // barrier state

  embed_kernel<<<SEQ * BATCH, 128, 0, stream>>>(ids, emb, x);
  wpack_kernel<<<4 * HID, 256, 0, stream>>>(Wih, Whh, Wp);

  lstm_kernel<<<NBLK, 256, 0, stream>>>(x, Wp, bias, ring, cnt, go);

  head_kernel<<<BATCH, 64, 0, stream>>>(ring + (size_t)SEQ * BATCH * HID,
                                        Wout, bout, out);
}